// Round 1
// baseline (857.349 us; speedup 1.0000x reference)
//
#include <hip/hip_runtime.h>
#include <math.h>

#define NN    50000
#define FDIM  200
#define E1N   400000
#define E2N   100000
#define EN    500000

typedef __attribute__((ext_vector_type(8))) short short8;
typedef __attribute__((ext_vector_type(4))) float f32x4;

// ---------------- workspace layout (4B units) ----------------
#define VALL_OFF   0            // 600 f
#define WALL_OFF   608          // 600 f
#define SCAL_OFF   1216         // NN*4 f = 200,000
#define RS_OFF     201216       // NN f (zeroed, atomic-accumulated)
#define CNT_OFF    251216       // NN int (zeroed)
#define FILL_OFF   301216       // NN int (zeroed, then = offsets)
#define INCL_OFF   351216       // NN int (offsets)
#define BSUM_OFF   401216       // 256 int
#define SORT_OFF   401472       // EN int2 = 1,000,000 ints
#define XB_OFF     1401472      // NN*200 bf16 = 10,000,000 ushort = 5,000,000 f
#define AB_OFF     6401472      // 200*600 bf16 = 120,000 ushort = 60,000 f
#define TSB_OFF    6461472      // NN*400 bf16 = 20,000,000 ushort = 10,000,000 f
#define WGT_OFF    16461472     // EN f = 500,000
// total 16,961,472 floats = ~68 MB

static __device__ __forceinline__ unsigned short f2bf(float f) {
    unsigned int u = __float_as_uint(f);
    unsigned int r = (u + 0x7fffu + ((u >> 16) & 1u)) >> 16;
    return (unsigned short)r;
}
static __device__ __forceinline__ float bf2f(unsigned short s) {
    return __uint_as_float((unsigned int)s << 16);
}

__global__ void k_coeffs(const float* __restrict__ a, const float* __restrict__ a2,
                         const float* __restrict__ mlpw,
                         float* __restrict__ vall, float* __restrict__ wall) {
    int k = blockIdx.x * blockDim.x + threadIdx.x;
    if (k >= 600) return;
    float v = 0.f, w = 0.f;
    for (int o = 0; o < FDIM; ++o) {
        float av = a[o * 600 + k];
        v += a2[o] * av;
        w += mlpw[o] * av;
    }
    vall[k] = v;
    wall[k] = w;
}

// per-node scalars ps,pd,qs,qd + fused x->bf16 conversion
__global__ __launch_bounds__(256) void k_node_scal(const float* __restrict__ x,
                                                   const float* __restrict__ vall,
                                                   const float* __restrict__ wall,
                                                   float* __restrict__ scal,
                                                   unsigned short* __restrict__ xb) {
    __shared__ float sv[1200];
    int tid = threadIdx.x;
    for (int i = tid; i < 1200; i += 256) sv[i] = (i < 600) ? vall[i] : wall[i - 600];
    __syncthreads();
    int lane = tid & 63;
    int n = blockIdx.x * 4 + (tid >> 6);
    float ps = 0.f, pd = 0.f, qs = 0.f, qd = 0.f;
    if (lane < 50) {
        float4 xv = *(const float4*)(x + (size_t)n * FDIM + lane * 4);
        float4 v1 = *(const float4*)(sv + lane * 4);
        float4 v2 = *(const float4*)(sv + 200 + lane * 4);
        float4 w1 = *(const float4*)(sv + 600 + lane * 4);
        float4 w2 = *(const float4*)(sv + 800 + lane * 4);
        ps = xv.x * v1.x + xv.y * v1.y + xv.z * v1.z + xv.w * v1.w;
        pd = xv.x * v2.x + xv.y * v2.y + xv.z * v2.z + xv.w * v2.w;
        qs = xv.x * w1.x + xv.y * w1.y + xv.z * w1.z + xv.w * w1.w;
        qd = xv.x * w2.x + xv.y * w2.y + xv.z * w2.z + xv.w * w2.w;
        ushort4 o;
        o.x = f2bf(xv.x); o.y = f2bf(xv.y); o.z = f2bf(xv.z); o.w = f2bf(xv.w);
        *(ushort4*)(xb + (size_t)n * FDIM + lane * 4) = o;
    }
    #pragma unroll
    for (int off = 32; off > 0; off >>= 1) {
        ps += __shfl_xor(ps, off);
        pd += __shfl_xor(pd, off);
        qs += __shfl_xor(qs, off);
        qd += __shfl_xor(qd, off);
    }
    if (lane == 0) {
        float4 r = make_float4(ps, pd, qs, qd);
        *(float4*)(scal + (size_t)n * 4) = r;
    }
}

__global__ __launch_bounds__(256) void k_cvt(const float* __restrict__ src,
                                             unsigned short* __restrict__ dst, int n4) {
    int i = blockIdx.x * 256 + threadIdx.x;
    if (i >= n4) return;
    float4 v = *(const float4*)(src + (size_t)i * 4);
    ushort4 o;
    o.x = f2bf(v.x); o.y = f2bf(v.y); o.z = f2bf(v.z); o.w = f2bf(v.w);
    *(ushort4*)(dst + (size_t)i * 4) = o;
}

__global__ __launch_bounds__(256) void k_hist(const int* __restrict__ edge,
                                              const int* __restrict__ edgenh,
                                              int* __restrict__ counts) {
    int g = blockIdx.x * 256 + threadIdx.x;
    if (g >= EN) return;
    int s = (g < E1N) ? edge[g] : edgenh[g - E1N];
    atomicAdd(counts + s, 1);
}

__global__ __launch_bounds__(256) void k_scan1(const int* __restrict__ counts,
                                               int* __restrict__ incl,
                                               int* __restrict__ bsums) {
    __shared__ int tmp[256];
    int g = blockIdx.x * 256 + threadIdx.x;
    int v = (g < NN) ? counts[g] : 0;
    tmp[threadIdx.x] = v;
    __syncthreads();
    for (int off = 1; off < 256; off <<= 1) {
        int t = (threadIdx.x >= off) ? tmp[threadIdx.x - off] : 0;
        __syncthreads();
        tmp[threadIdx.x] += t;
        __syncthreads();
    }
    if (g < NN) incl[g] = tmp[threadIdx.x];
    if (threadIdx.x == 255) bsums[blockIdx.x] = tmp[255];
}

__global__ __launch_bounds__(256) void k_scan2(int* __restrict__ bsums, int nb) {
    __shared__ int tmp[256];
    int v = (threadIdx.x < nb) ? bsums[threadIdx.x] : 0;
    tmp[threadIdx.x] = v;
    __syncthreads();
    for (int off = 1; off < 256; off <<= 1) {
        int t = (threadIdx.x >= off) ? tmp[threadIdx.x - off] : 0;
        __syncthreads();
        tmp[threadIdx.x] += t;
        __syncthreads();
    }
    if (threadIdx.x < nb) bsums[threadIdx.x] = tmp[threadIdx.x] - v;  // exclusive
}

// incl -> exclusive offsets; also copy into fill (running cursor for scatter)
__global__ __launch_bounds__(256) void k_scan3(const int* __restrict__ counts,
                                               int* __restrict__ incl,
                                               const int* __restrict__ bsums,
                                               int* __restrict__ fill) {
    int g = blockIdx.x * 256 + threadIdx.x;
    if (g >= NN) return;
    int v = incl[g] - counts[g] + bsums[blockIdx.x];
    incl[g] = v;
    fill[g] = v;
}

// scatter (e, dst) pairs grouped by src
__global__ __launch_bounds__(256) void k_scatter(const int* __restrict__ edge,
                                                 const int* __restrict__ edgenh,
                                                 int* __restrict__ fill,
                                                 int2* __restrict__ sorted2) {
    int g = blockIdx.x * 256 + threadIdx.x;
    if (g >= EN) return;
    int s, d;
    if (g < E1N) { s = edge[g]; d = edge[E1N + g]; }
    else { s = edgenh[g - E1N]; d = edgenh[E2N + (g - E1N)]; }
    int pos = atomicAdd(fill + s, 1);
    sorted2[pos] = make_int2(g, d);
}

// NEW phase A: one wave per edge, ORIGINAL edge order (streaming-coalesced ee reads).
// Computes the full attention weight per edge; writes wgt[e] and atomically
// accumulates rowsum[src]. Shuffle-reduction latency hides behind 500K independent waves.
__global__ __launch_bounds__(256) void k_edge_wgt(const int* __restrict__ edge,
                                                  const int* __restrict__ edgenh,
                                                  const float* __restrict__ ee,
                                                  const float* __restrict__ eenh,
                                                  const float* __restrict__ vall,
                                                  const float* __restrict__ wall,
                                                  const float* __restrict__ scal,
                                                  const float* __restrict__ mlpb,
                                                  float* __restrict__ wgtbuf,
                                                  float* __restrict__ rowsum) {
    int tid = threadIdx.x, lane = tid & 63;
    int e = blockIdx.x * 4 + (tid >> 6);          // grid = EN/4 exactly
    int s, d;
    const float* erow;
    if (e < E1N) {
        s = edge[e]; d = edge[E1N + e];
        erow = ee + (size_t)e * FDIM;
    } else {
        int f = e - E1N;
        s = edgenh[f]; d = edgenh[E2N + f];
        erow = eenh + (size_t)f * FDIM;
    }
    float pe = 0.f, qe = 0.f;
    if (lane < 50) {
        float4 ev = *(const float4*)(erow + lane * 4);
        float4 v3 = *(const float4*)(vall + 400 + lane * 4);
        float4 w3 = *(const float4*)(wall + 400 + lane * 4);
        pe = ev.x * v3.x + ev.y * v3.y + ev.z * v3.z + ev.w * v3.w;
        qe = ev.x * w3.x + ev.y * w3.y + ev.z * w3.z + ev.w * w3.w;
    }
    #pragma unroll
    for (int off = 32; off > 0; off >>= 1) {
        pe += __shfl_xor(pe, off);
        qe += __shfl_xor(qe, off);
    }
    float4 ss = *(const float4*)(scal + (size_t)s * 4);
    float4 sd = *(const float4*)(scal + (size_t)d * 4);
    float z1 = ss.x + sd.y + pe;
    float z2 = ss.z + sd.w + qe + mlpb[0];
    float l = z1 > 0.f ? z1 : 0.2f * z1;
    float e2 = __expf(2.f * z2);
    float t = 1.f - 2.f * __builtin_amdgcn_rcpf(e2 + 1.f);
    float w = __expf(l * t * (-1.f / (float)EN));
    if (lane == 0) {
        wgtbuf[e] = w;
        atomicAdd(rowsum + s, w);
    }
}

// NEW phase B: pure accumulation. No cross-lane ops, no data-dependent load chain:
// sorted2 addresses are induction-based, wgt is a broadcast 4B L2 hit, body is FMA.
__global__ __launch_bounds__(256) void k_csr2(const int2* __restrict__ sorted2,
                                              const int* __restrict__ offs,
                                              const int* __restrict__ counts,
                                              const float* __restrict__ ee,
                                              const float* __restrict__ eenh,
                                              const unsigned short* __restrict__ xb,
                                              const float* __restrict__ wgtbuf,
                                              const float* __restrict__ rowsum,
                                              unsigned short* __restrict__ Tsb) {
    int tid = threadIdx.x, lane = tid & 63;
    int n = blockIdx.x * 4 + (tid >> 6);
    int beg = offs[n], cnt = counts[n];
    float ax0 = 0, ax1 = 0, ax2 = 0, ax3 = 0;
    float ae0 = 0, ae1 = 0, ae2 = 0, ae3 = 0;
    #pragma unroll 2
    for (int i = 0; i < cnt; ++i) {
        int2 ed = sorted2[beg + i];
        float wv = wgtbuf[ed.x];
        const float* erow = (ed.x < E1N) ? ee + (size_t)ed.x * FDIM
                                         : eenh + (size_t)(ed.x - E1N) * FDIM;
        float4 ev = make_float4(0, 0, 0, 0), xv = ev;
        if (lane < 50) {
            ev = *(const float4*)(erow + lane * 4);
            ushort4 xu = *(const ushort4*)(xb + (size_t)ed.y * FDIM + lane * 4);
            xv.x = bf2f(xu.x); xv.y = bf2f(xu.y); xv.z = bf2f(xu.z); xv.w = bf2f(xu.w);
        }
        ax0 += wv * xv.x; ax1 += wv * xv.y; ax2 += wv * xv.z; ax3 += wv * xv.w;
        ae0 += wv * ev.x; ae1 += wv * ev.y; ae2 += wv * ev.z; ae3 += wv * ev.w;
    }
    float inv = (cnt > 0) ? __builtin_amdgcn_rcpf(rowsum[n]) : 0.f;
    if (lane < 50) {
        ushort4 o1, o2;
        o1.x = f2bf(ax0 * inv); o1.y = f2bf(ax1 * inv);
        o1.z = f2bf(ax2 * inv); o1.w = f2bf(ax3 * inv);
        o2.x = f2bf(ae0 * inv); o2.y = f2bf(ae1 * inv);
        o2.z = f2bf(ae2 * inv); o2.w = f2bf(ae3 * inv);
        *(ushort4*)(Tsb + (size_t)n * 400 + lane * 4) = o1;
        *(ushort4*)(Tsb + (size_t)n * 400 + 200 + lane * 4) = o2;
    }
}

// single fused GEMM: out = elu([x | T/rs] @ A^T), rowsum==0 -> 0
// K padded to 640: [0,200) from xb, [224,624) from Tsb, rest zero. B from ab (stride 600).
// XCD-chunked block swizzle: grid 3128 = 8*391; each XCD gets a consecutive tile
// range so the 4 column-sibling blocks of a row share the A-panel in one XCD L2.
__global__ __launch_bounds__(256) void k_gemm_fused(const unsigned short* __restrict__ xb,
                                                    const unsigned short* __restrict__ tsb,
                                                    const unsigned short* __restrict__ ab,
                                                    const float* __restrict__ rowsum,
                                                    float* __restrict__ out) {
    __shared__ unsigned short Al[64][40];
    __shared__ unsigned short Bl[64][40];
    int tid = threadIdx.x, w = tid >> 6, lane = tid & 63;
    int h = blockIdx.y * 4 + blockIdx.x;          // linear hw id, x fastest
    int g = (h & 7) * 391 + (h >> 3);             // bijective: 3128 = 8*391
    int by = g >> 2, bx = g & 3;
    f32x4 acc[4] = {};
    int r = tid >> 2, c = tid & 3;
    int arow = by * 64 + r;
    int brow = bx * 64 + r;
    bool inA = arow < NN;
    bool inB = brow < 200;
    const unsigned short* aPx = xb + (size_t)arow * 200;
    const unsigned short* aPt = tsb + (size_t)arow * 400;
    const unsigned short* bP = ab + (size_t)brow * 600;
    for (int k0 = 0; k0 < 640; k0 += 32) {
        int gk = k0 + c * 8;
        uint4 av = make_uint4(0, 0, 0, 0), bv = av;
        if (gk < 200) {
            if (inA) av = *(const uint4*)(aPx + gk);
            if (inB) bv = *(const uint4*)(bP + gk);
        } else if (gk >= 224 && gk < 624) {
            if (inA) av = *(const uint4*)(aPt + (gk - 224));
            if (inB) bv = *(const uint4*)(bP + gk - 24);  // a col 200 + (gk-224)
        }
        *(uint4*)&Al[r][c * 8] = av;
        *(uint4*)&Bl[r][c * 8] = bv;
        __syncthreads();
        short8 af = *(short8*)&Al[w * 16 + (lane & 15)][(lane >> 4) * 8];
        #pragma unroll
        for (int ct = 0; ct < 4; ++ct) {
            short8 bf = *(short8*)&Bl[ct * 16 + (lane & 15)][(lane >> 4) * 8];
            acc[ct] = __builtin_amdgcn_mfma_f32_16x16x32_bf16(af, bf, acc[ct], 0, 0, 0);
        }
        __syncthreads();
    }
    #pragma unroll
    for (int ct = 0; ct < 4; ++ct) {
        #pragma unroll
        for (int rr = 0; rr < 4; ++rr) {
            int grow = by * 64 + w * 16 + (lane >> 4) * 4 + rr;
            int gcol = bx * 64 + ct * 16 + (lane & 15);
            if (grow < NN && gcol < 200) {
                float rsv = rowsum[grow];
                float hh = acc[ct][rr];
                float o = (rsv == 0.f) ? 0.f : (hh > 0.f ? hh : expm1f(hh));
                out[(size_t)grow * 200 + gcol] = o;
            }
        }
    }
}

extern "C" void kernel_launch(void* const* d_in, const int* in_sizes, int n_in,
                              void* d_out, int out_size, void* d_ws, size_t ws_size,
                              hipStream_t stream) {
    const float* x      = (const float*)d_in[0];
    const int*   edge   = (const int*)d_in[1];
    const float* ee     = (const float*)d_in[2];
    const int*   edgenh = (const int*)d_in[3];
    const float* eenh   = (const float*)d_in[4];
    const float* a      = (const float*)d_in[5];
    const float* a2     = (const float*)d_in[6];
    const float* mlpw   = (const float*)d_in[7];
    const float* mlpb   = (const float*)d_in[8];

    float* ws = (float*)d_ws;
    float* vall   = ws + VALL_OFF;
    float* wall   = ws + WALL_OFF;
    float* scal   = ws + SCAL_OFF;
    float* rowsum = ws + RS_OFF;
    int*   counts = (int*)(ws + CNT_OFF);
    int*   fill   = (int*)(ws + FILL_OFF);
    int*   incl   = (int*)(ws + INCL_OFF);
    int*   bsums  = (int*)(ws + BSUM_OFF);
    int2*  sorted2 = (int2*)(ws + SORT_OFF);
    unsigned short* xb  = (unsigned short*)(ws + XB_OFF);
    unsigned short* ab  = (unsigned short*)(ws + AB_OFF);
    unsigned short* tsb = (unsigned short*)(ws + TSB_OFF);
    float* wgtbuf = ws + WGT_OFF;

    // zero rowsum + counts + fill (contiguous: RS_OFF, CNT_OFF, FILL_OFF)
    hipMemsetAsync(rowsum, 0, (size_t)(3 * NN) * sizeof(int), stream);

    k_coeffs<<<3, 256, 0, stream>>>(a, a2, mlpw, vall, wall);
    k_node_scal<<<NN / 4, 256, 0, stream>>>(x, vall, wall, scal, xb);
    k_cvt<<<(200 * 600 / 4 + 255) / 256, 256, 0, stream>>>(a, ab, 200 * 600 / 4);

    k_hist<<<(EN + 255) / 256, 256, 0, stream>>>(edge, edgenh, counts);
    int nb = (NN + 255) / 256;
    k_scan1<<<nb, 256, 0, stream>>>(counts, incl, bsums);
    k_scan2<<<1, 256, 0, stream>>>(bsums, nb);
    k_scan3<<<nb, 256, 0, stream>>>(counts, incl, bsums, fill);
    k_scatter<<<(EN + 255) / 256, 256, 0, stream>>>(edge, edgenh, fill, sorted2);

    k_edge_wgt<<<EN / 4, 256, 0, stream>>>(edge, edgenh, ee, eenh,
                                           vall, wall, scal, mlpb, wgtbuf, rowsum);

    k_csr2<<<NN / 4, 256, 0, stream>>>(sorted2, incl, counts, ee, eenh, xb,
                                       wgtbuf, rowsum, tsb);

    dim3 gg(4, (NN + 63) / 64);
    k_gemm_fused<<<gg, 256, 0, stream>>>(xb, tsb, ab, rowsum, (float*)d_out);
}

// Round 2
// 727.593 us; speedup vs baseline: 1.1783x; 1.1783x over previous
//
#include <hip/hip_runtime.h>
#include <math.h>

#define NN    50000
#define FDIM  200
#define E1N   400000
#define E2N   100000
#define EN    500000

typedef __attribute__((ext_vector_type(8))) short short8;
typedef __attribute__((ext_vector_type(4))) float f32x4;

// ---------------- workspace layout (4B units) ----------------
#define VALL_OFF   0            // 600 f
#define WALL_OFF   608          // 600 f
#define SCAL_OFF   1216         // NN*4 f = 200,000
#define RS_OFF     201216       // NN f
#define CNT_OFF    251216       // NN int (zeroed)
#define FILL_OFF   301216       // NN int (zeroed, then = offsets)
#define INCL_OFF   351216       // NN int (offsets)
#define BSUM_OFF   401216       // 256 int
#define SORT_OFF   401472       // EN int2 = 1,000,000 ints
#define XB_OFF     1401472      // NN*200 bf16 = 10,000,000 ushort = 5,000,000 f
#define AB_OFF     6401472      // 200*600 bf16 = 120,000 ushort = 60,000 f
#define TSB_OFF    6461472      // NN*400 bf16 = 20,000,000 ushort = 10,000,000 f
// total 16,461,472 floats = ~66 MB

static __device__ __forceinline__ unsigned short f2bf(float f) {
    unsigned int u = __float_as_uint(f);
    unsigned int r = (u + 0x7fffu + ((u >> 16) & 1u)) >> 16;
    return (unsigned short)r;
}
static __device__ __forceinline__ float bf2f(unsigned short s) {
    return __uint_as_float((unsigned int)s << 16);
}

// ---- DPP wave-64 sum: 6 VALU-latency steps (vs 6 DS-latency shfl_xor) ----
// row_shr:1/2/4/8 accumulate within each 16-lane row (row sum lands in lane 15
// of each row); row_bcast:15 (rows 1,3) then row_bcast:31 (rows 2,3) fold rows;
// lane 63 holds the full sum. Standard GCN3/CDNA sequence (rocPRIM).
#define DPP_ADD(x, ctrl, rmask) \
    x += __int_as_float(__builtin_amdgcn_update_dpp(0, __float_as_int(x), ctrl, rmask, 0xf, true))

static __device__ __forceinline__ float wave_sum_bcast(float x) {
    DPP_ADD(x, 0x111, 0xf);   // row_shr:1
    DPP_ADD(x, 0x112, 0xf);   // row_shr:2
    DPP_ADD(x, 0x114, 0xf);   // row_shr:4
    DPP_ADD(x, 0x118, 0xf);   // row_shr:8
    DPP_ADD(x, 0x142, 0xa);   // row_bcast:15 -> rows 1,3
    DPP_ADD(x, 0x143, 0xc);   // row_bcast:31 -> rows 2,3
    return __int_as_float(__builtin_amdgcn_readlane(__float_as_int(x), 63));
}

__global__ void k_coeffs(const float* __restrict__ a, const float* __restrict__ a2,
                         const float* __restrict__ mlpw,
                         float* __restrict__ vall, float* __restrict__ wall) {
    int k = blockIdx.x * blockDim.x + threadIdx.x;
    if (k >= 600) return;
    float v = 0.f, w = 0.f;
    for (int o = 0; o < FDIM; ++o) {
        float av = a[o * 600 + k];
        v += a2[o] * av;
        w += mlpw[o] * av;
    }
    vall[k] = v;
    wall[k] = w;
}

// per-node scalars ps,pd,qs,qd + fused x->bf16 conversion
__global__ __launch_bounds__(256) void k_node_scal(const float* __restrict__ x,
                                                   const float* __restrict__ vall,
                                                   const float* __restrict__ wall,
                                                   float* __restrict__ scal,
                                                   unsigned short* __restrict__ xb) {
    __shared__ float sv[1200];
    int tid = threadIdx.x;
    for (int i = tid; i < 1200; i += 256) sv[i] = (i < 600) ? vall[i] : wall[i - 600];
    __syncthreads();
    int lane = tid & 63;
    int n = blockIdx.x * 4 + (tid >> 6);
    float ps = 0.f, pd = 0.f, qs = 0.f, qd = 0.f;
    if (lane < 50) {
        float4 xv = *(const float4*)(x + (size_t)n * FDIM + lane * 4);
        float4 v1 = *(const float4*)(sv + lane * 4);
        float4 v2 = *(const float4*)(sv + 200 + lane * 4);
        float4 w1 = *(const float4*)(sv + 600 + lane * 4);
        float4 w2 = *(const float4*)(sv + 800 + lane * 4);
        ps = xv.x * v1.x + xv.y * v1.y + xv.z * v1.z + xv.w * v1.w;
        pd = xv.x * v2.x + xv.y * v2.y + xv.z * v2.z + xv.w * v2.w;
        qs = xv.x * w1.x + xv.y * w1.y + xv.z * w1.z + xv.w * w1.w;
        qd = xv.x * w2.x + xv.y * w2.y + xv.z * w2.z + xv.w * w2.w;
        ushort4 o;
        o.x = f2bf(xv.x); o.y = f2bf(xv.y); o.z = f2bf(xv.z); o.w = f2bf(xv.w);
        *(ushort4*)(xb + (size_t)n * FDIM + lane * 4) = o;
    }
    ps = wave_sum_bcast(ps);
    pd = wave_sum_bcast(pd);
    qs = wave_sum_bcast(qs);
    qd = wave_sum_bcast(qd);
    if (lane == 0) {
        float4 r = make_float4(ps, pd, qs, qd);
        *(float4*)(scal + (size_t)n * 4) = r;
    }
}

__global__ __launch_bounds__(256) void k_cvt(const float* __restrict__ src,
                                             unsigned short* __restrict__ dst, int n4) {
    int i = blockIdx.x * 256 + threadIdx.x;
    if (i >= n4) return;
    float4 v = *(const float4*)(src + (size_t)i * 4);
    ushort4 o;
    o.x = f2bf(v.x); o.y = f2bf(v.y); o.z = f2bf(v.z); o.w = f2bf(v.w);
    *(ushort4*)(dst + (size_t)i * 4) = o;
}

__global__ __launch_bounds__(256) void k_hist(const int* __restrict__ edge,
                                              const int* __restrict__ edgenh,
                                              int* __restrict__ counts) {
    int g = blockIdx.x * 256 + threadIdx.x;
    if (g >= EN) return;
    int s = (g < E1N) ? edge[g] : edgenh[g - E1N];
    atomicAdd(counts + s, 1);
}

__global__ __launch_bounds__(256) void k_scan1(const int* __restrict__ counts,
                                               int* __restrict__ incl,
                                               int* __restrict__ bsums) {
    __shared__ int tmp[256];
    int g = blockIdx.x * 256 + threadIdx.x;
    int v = (g < NN) ? counts[g] : 0;
    tmp[threadIdx.x] = v;
    __syncthreads();
    for (int off = 1; off < 256; off <<= 1) {
        int t = (threadIdx.x >= off) ? tmp[threadIdx.x - off] : 0;
        __syncthreads();
        tmp[threadIdx.x] += t;
        __syncthreads();
    }
    if (g < NN) incl[g] = tmp[threadIdx.x];
    if (threadIdx.x == 255) bsums[blockIdx.x] = tmp[255];
}

__global__ __launch_bounds__(256) void k_scan2(int* __restrict__ bsums, int nb) {
    __shared__ int tmp[256];
    int v = (threadIdx.x < nb) ? bsums[threadIdx.x] : 0;
    tmp[threadIdx.x] = v;
    __syncthreads();
    for (int off = 1; off < 256; off <<= 1) {
        int t = (threadIdx.x >= off) ? tmp[threadIdx.x - off] : 0;
        __syncthreads();
        tmp[threadIdx.x] += t;
        __syncthreads();
    }
    if (threadIdx.x < nb) bsums[threadIdx.x] = tmp[threadIdx.x] - v;  // exclusive
}

// incl -> exclusive offsets; also copy into fill (running cursor for scatter)
__global__ __launch_bounds__(256) void k_scan3(const int* __restrict__ counts,
                                               int* __restrict__ incl,
                                               const int* __restrict__ bsums,
                                               int* __restrict__ fill) {
    int g = blockIdx.x * 256 + threadIdx.x;
    if (g >= NN) return;
    int v = incl[g] - counts[g] + bsums[blockIdx.x];
    incl[g] = v;
    fill[g] = v;
}

// scatter (e, dst) pairs grouped by src
__global__ __launch_bounds__(256) void k_scatter(const int* __restrict__ edge,
                                                 const int* __restrict__ edgenh,
                                                 int* __restrict__ fill,
                                                 int2* __restrict__ sorted2) {
    int g = blockIdx.x * 256 + threadIdx.x;
    if (g >= EN) return;
    int s, d;
    if (g < E1N) { s = edge[g]; d = edge[E1N + g]; }
    else { s = edgenh[g - E1N]; d = edgenh[E2N + (g - E1N)]; }
    int pos = atomicAdd(fill + s, 1);
    sorted2[pos] = make_int2(g, d);
}

// Fused per-node pass: weights + accumulation in ONE read of ee (structural
// minimum traffic). DPP reduce (VALU latency) replaces the shfl_xor DS chain;
// 2-deep explicit pipeline keeps next edge's rows in flight during the reduce.
__global__ __launch_bounds__(256) void k_csr(const int2* __restrict__ sorted2,
                                             const int* __restrict__ offs,
                                             const int* __restrict__ counts,
                                             const float* __restrict__ ee,
                                             const float* __restrict__ eenh,
                                             const unsigned short* __restrict__ xb,
                                             const float* __restrict__ vall,
                                             const float* __restrict__ wall,
                                             const float* __restrict__ scal,
                                             const float* __restrict__ mlpb,
                                             float* __restrict__ rowsum,
                                             unsigned short* __restrict__ Tsb) {
    int tid = threadIdx.x, lane = tid & 63;
    int n = blockIdx.x * 4 + (tid >> 6);
    float4 v3 = make_float4(0, 0, 0, 0), w3 = v3;
    if (lane < 50) {
        v3 = *(const float4*)(vall + 400 + lane * 4);
        w3 = *(const float4*)(wall + 400 + lane * 4);
    }
    float4 sc_n = *(const float4*)(scal + (size_t)n * 4);
    float mb = mlpb[0];
    int beg = offs[n], cnt = counts[n];
    float accx0 = 0, accx1 = 0, accx2 = 0, accx3 = 0;
    float acce0 = 0, acce1 = 0, acce2 = 0, acce3 = 0;
    float rs = 0.f;
    // prologue: edge 0 record + rows
    int2 ed = (cnt > 0) ? sorted2[beg] : make_int2(0, 0);
    float4 evc = make_float4(0, 0, 0, 0), xvc = evc;
    if (cnt > 0 && lane < 50) {
        const float* er = (ed.x < E1N) ? ee + (size_t)ed.x * FDIM
                                       : eenh + (size_t)(ed.x - E1N) * FDIM;
        evc = *(const float4*)(er + lane * 4);
        ushort4 xu = *(const ushort4*)(xb + (size_t)ed.y * FDIM + lane * 4);
        xvc.x = bf2f(xu.x); xvc.y = bf2f(xu.y); xvc.z = bf2f(xu.z); xvc.w = bf2f(xu.w);
    }
    for (int i = 0; i < cnt; ++i) {
        // prefetch edge i+1 (record + rows) before the reduce of edge i
        int2 edn = (i + 1 < cnt) ? sorted2[beg + i + 1] : ed;
        float4 evn = make_float4(0, 0, 0, 0), xvn = evn;
        if (i + 1 < cnt && lane < 50) {
            const float* ern = (edn.x < E1N) ? ee + (size_t)edn.x * FDIM
                                             : eenh + (size_t)(edn.x - E1N) * FDIM;
            evn = *(const float4*)(ern + lane * 4);
            ushort4 xu = *(const ushort4*)(xb + (size_t)edn.y * FDIM + lane * 4);
            xvn.x = bf2f(xu.x); xvn.y = bf2f(xu.y); xvn.z = bf2f(xu.z); xvn.w = bf2f(xu.w);
        }
        float pe = evc.x * v3.x + evc.y * v3.y + evc.z * v3.z + evc.w * v3.w;
        float qe = evc.x * w3.x + evc.y * w3.y + evc.z * w3.z + evc.w * w3.w;
        pe = wave_sum_bcast(pe);
        qe = wave_sum_bcast(qe);
        float4 sd = *(const float4*)(scal + (size_t)ed.y * 4);
        float z1 = sc_n.x + sd.y + pe;
        float z2 = sc_n.z + sd.w + qe + mb;
        float l = z1 > 0.f ? z1 : 0.2f * z1;
        float e2 = __expf(2.f * z2);
        float t = 1.f - 2.f * __builtin_amdgcn_rcpf(e2 + 1.f);
        float wgt = __expf(l * t * (-1.f / (float)EN));
        rs += wgt;
        accx0 += wgt * xvc.x; accx1 += wgt * xvc.y; accx2 += wgt * xvc.z; accx3 += wgt * xvc.w;
        acce0 += wgt * evc.x; acce1 += wgt * evc.y; acce2 += wgt * evc.z; acce3 += wgt * evc.w;
        ed = edn; evc = evn; xvc = xvn;
    }
    if (lane == 0) rowsum[n] = rs;
    float inv = (cnt > 0) ? __builtin_amdgcn_rcpf(rs) : 0.f;
    if (lane < 50) {
        ushort4 o1, o2;
        o1.x = f2bf(accx0 * inv); o1.y = f2bf(accx1 * inv);
        o1.z = f2bf(accx2 * inv); o1.w = f2bf(accx3 * inv);
        o2.x = f2bf(acce0 * inv); o2.y = f2bf(acce1 * inv);
        o2.z = f2bf(acce2 * inv); o2.w = f2bf(acce3 * inv);
        *(ushort4*)(Tsb + (size_t)n * 400 + lane * 4) = o1;
        *(ushort4*)(Tsb + (size_t)n * 400 + 200 + lane * 4) = o2;
    }
}

// single fused GEMM: out = elu([x | T/rs] @ A^T), rowsum==0 -> 0
// K padded to 640: [0,200) from xb, [224,624) from Tsb, rest zero. B from ab (stride 600).
// XCD-chunked block swizzle: grid 3128 = 8*391; each XCD gets a consecutive tile
// range so the 4 column-sibling blocks of a row share the A-panel in one XCD L2.
__global__ __launch_bounds__(256) void k_gemm_fused(const unsigned short* __restrict__ xb,
                                                    const unsigned short* __restrict__ tsb,
                                                    const unsigned short* __restrict__ ab,
                                                    const float* __restrict__ rowsum,
                                                    float* __restrict__ out) {
    __shared__ unsigned short Al[64][40];
    __shared__ unsigned short Bl[64][40];
    int tid = threadIdx.x, w = tid >> 6, lane = tid & 63;
    int h = blockIdx.y * 4 + blockIdx.x;          // linear hw id, x fastest
    int g = (h & 7) * 391 + (h >> 3);             // bijective: 3128 = 8*391
    int by = g >> 2, bx = g & 3;
    f32x4 acc[4] = {};
    int r = tid >> 2, c = tid & 3;
    int arow = by * 64 + r;
    int brow = bx * 64 + r;
    bool inA = arow < NN;
    bool inB = brow < 200;
    const unsigned short* aPx = xb + (size_t)arow * 200;
    const unsigned short* aPt = tsb + (size_t)arow * 400;
    const unsigned short* bP = ab + (size_t)brow * 600;
    for (int k0 = 0; k0 < 640; k0 += 32) {
        int gk = k0 + c * 8;
        uint4 av = make_uint4(0, 0, 0, 0), bv = av;
        if (gk < 200) {
            if (inA) av = *(const uint4*)(aPx + gk);
            if (inB) bv = *(const uint4*)(bP + gk);
        } else if (gk >= 224 && gk < 624) {
            if (inA) av = *(const uint4*)(aPt + (gk - 224));
            if (inB) bv = *(const uint4*)(bP + gk - 24);  // a col 200 + (gk-224)
        }
        *(uint4*)&Al[r][c * 8] = av;
        *(uint4*)&Bl[r][c * 8] = bv;
        __syncthreads();
        short8 af = *(short8*)&Al[w * 16 + (lane & 15)][(lane >> 4) * 8];
        #pragma unroll
        for (int ct = 0; ct < 4; ++ct) {
            short8 bf = *(short8*)&Bl[ct * 16 + (lane & 15)][(lane >> 4) * 8];
            acc[ct] = __builtin_amdgcn_mfma_f32_16x16x32_bf16(af, bf, acc[ct], 0, 0, 0);
        }
        __syncthreads();
    }
    #pragma unroll
    for (int ct = 0; ct < 4; ++ct) {
        #pragma unroll
        for (int rr = 0; rr < 4; ++rr) {
            int grow = by * 64 + w * 16 + (lane >> 4) * 4 + rr;
            int gcol = bx * 64 + ct * 16 + (lane & 15);
            if (grow < NN && gcol < 200) {
                float rsv = rowsum[grow];
                float hh = acc[ct][rr];
                float o = (rsv == 0.f) ? 0.f : (hh > 0.f ? hh : expm1f(hh));
                out[(size_t)grow * 200 + gcol] = o;
            }
        }
    }
}

extern "C" void kernel_launch(void* const* d_in, const int* in_sizes, int n_in,
                              void* d_out, int out_size, void* d_ws, size_t ws_size,
                              hipStream_t stream) {
    const float* x      = (const float*)d_in[0];
    const int*   edge   = (const int*)d_in[1];
    const float* ee     = (const float*)d_in[2];
    const int*   edgenh = (const int*)d_in[3];
    const float* eenh   = (const float*)d_in[4];
    const float* a      = (const float*)d_in[5];
    const float* a2     = (const float*)d_in[6];
    const float* mlpw   = (const float*)d_in[7];
    const float* mlpb   = (const float*)d_in[8];

    float* ws = (float*)d_ws;
    float* vall   = ws + VALL_OFF;
    float* wall   = ws + WALL_OFF;
    float* scal   = ws + SCAL_OFF;
    float* rowsum = ws + RS_OFF;
    int*   counts = (int*)(ws + CNT_OFF);
    int*   fill   = (int*)(ws + FILL_OFF);
    int*   incl   = (int*)(ws + INCL_OFF);
    int*   bsums  = (int*)(ws + BSUM_OFF);
    int2*  sorted2 = (int2*)(ws + SORT_OFF);
    unsigned short* xb  = (unsigned short*)(ws + XB_OFF);
    unsigned short* ab  = (unsigned short*)(ws + AB_OFF);
    unsigned short* tsb = (unsigned short*)(ws + TSB_OFF);

    hipMemsetAsync(counts, 0, (size_t)(2 * NN) * sizeof(int), stream);

    k_coeffs<<<3, 256, 0, stream>>>(a, a2, mlpw, vall, wall);
    k_node_scal<<<NN / 4, 256, 0, stream>>>(x, vall, wall, scal, xb);
    k_cvt<<<(200 * 600 / 4 + 255) / 256, 256, 0, stream>>>(a, ab, 200 * 600 / 4);

    k_hist<<<(EN + 255) / 256, 256, 0, stream>>>(edge, edgenh, counts);
    int nb = (NN + 255) / 256;
    k_scan1<<<nb, 256, 0, stream>>>(counts, incl, bsums);
    k_scan2<<<1, 256, 0, stream>>>(bsums, nb);
    k_scan3<<<nb, 256, 0, stream>>>(counts, incl, bsums, fill);
    k_scatter<<<(EN + 255) / 256, 256, 0, stream>>>(edge, edgenh, fill, sorted2);

    k_csr<<<NN / 4, 256, 0, stream>>>(sorted2, incl, counts, ee, eenh, xb,
                                      vall, wall, scal, mlpb, rowsum, tsb);

    dim3 gg(4, (NN + 63) / 64);
    k_gemm_fused<<<gg, 256, 0, stream>>>(xb, tsb, ab, rowsum, (float*)d_out);
}

// Round 3
// 683.141 us; speedup vs baseline: 1.2550x; 1.0651x over previous
//
#include <hip/hip_runtime.h>
#include <math.h>

#define NN    50000
#define FDIM  200
#define E1N   400000
#define E2N   100000
#define EN    500000

typedef __attribute__((ext_vector_type(8))) short short8;
typedef __attribute__((ext_vector_type(4))) float f32x4;

// ---------------- workspace layout (4B units) ----------------
#define VALL_OFF   0            // 600 f
#define WALL_OFF   608          // 600 f
#define SCAL_OFF   1216         // NN*4 f = 200,000
#define RS_OFF     201216       // NN f
#define CNT_OFF    251216       // NN int (zeroed)
#define FILL_OFF   301216       // NN int (zeroed, then = offsets)
#define INCL_OFF   351216       // NN int (offsets)
#define BSUM_OFF   401216       // 256 int
#define SORT_OFF   401472       // EN int2 = 1,000,000 ints
#define XB_OFF     1401472      // NN*200 bf16 = 10,000,000 ushort = 5,000,000 f
#define AB_OFF     6401472      // 200*600 bf16 = 120,000 ushort = 60,000 f
#define TSB_OFF    6461472      // NN*400 bf16 = 20,000,000 ushort = 10,000,000 f
// total 16,461,472 floats = ~66 MB

static __device__ __forceinline__ unsigned short f2bf(float f) {
    unsigned int u = __float_as_uint(f);
    unsigned int r = (u + 0x7fffu + ((u >> 16) & 1u)) >> 16;
    return (unsigned short)r;
}
static __device__ __forceinline__ float bf2f(unsigned short s) {
    return __uint_as_float((unsigned int)s << 16);
}

// ---- DPP wave-64 sum (VALU-latency, 6 steps); result broadcast via readlane 63 ----
#define DPP_ADD(x, ctrl, rmask) \
    x += __int_as_float(__builtin_amdgcn_update_dpp(0, __float_as_int(x), ctrl, rmask, 0xf, true))

static __device__ __forceinline__ float wave_sum_bcast(float x) {
    DPP_ADD(x, 0x111, 0xf);   // row_shr:1
    DPP_ADD(x, 0x112, 0xf);   // row_shr:2
    DPP_ADD(x, 0x114, 0xf);   // row_shr:4
    DPP_ADD(x, 0x118, 0xf);   // row_shr:8
    DPP_ADD(x, 0x142, 0xa);   // row_bcast:15 -> rows 1,3
    DPP_ADD(x, 0x143, 0xc);   // row_bcast:31 -> rows 2,3
    return __int_as_float(__builtin_amdgcn_readlane(__float_as_int(x), 63));
}

static __device__ __forceinline__ float readlane_f(float v, int l) {
    return __int_as_float(__builtin_amdgcn_readlane(__float_as_int(v), l));
}

__global__ void k_coeffs(const float* __restrict__ a, const float* __restrict__ a2,
                         const float* __restrict__ mlpw,
                         float* __restrict__ vall, float* __restrict__ wall) {
    int k = blockIdx.x * blockDim.x + threadIdx.x;
    if (k >= 600) return;
    float v = 0.f, w = 0.f;
    for (int o = 0; o < FDIM; ++o) {
        float av = a[o * 600 + k];
        v += a2[o] * av;
        w += mlpw[o] * av;
    }
    vall[k] = v;
    wall[k] = w;
}

// per-node scalars ps,pd,qs,qd + fused x->bf16 conversion
__global__ __launch_bounds__(256) void k_node_scal(const float* __restrict__ x,
                                                   const float* __restrict__ vall,
                                                   const float* __restrict__ wall,
                                                   float* __restrict__ scal,
                                                   unsigned short* __restrict__ xb) {
    __shared__ float sv[1200];
    int tid = threadIdx.x;
    for (int i = tid; i < 1200; i += 256) sv[i] = (i < 600) ? vall[i] : wall[i - 600];
    __syncthreads();
    int lane = tid & 63;
    int n = blockIdx.x * 4 + (tid >> 6);
    float ps = 0.f, pd = 0.f, qs = 0.f, qd = 0.f;
    if (lane < 50) {
        float4 xv = *(const float4*)(x + (size_t)n * FDIM + lane * 4);
        float4 v1 = *(const float4*)(sv + lane * 4);
        float4 v2 = *(const float4*)(sv + 200 + lane * 4);
        float4 w1 = *(const float4*)(sv + 600 + lane * 4);
        float4 w2 = *(const float4*)(sv + 800 + lane * 4);
        ps = xv.x * v1.x + xv.y * v1.y + xv.z * v1.z + xv.w * v1.w;
        pd = xv.x * v2.x + xv.y * v2.y + xv.z * v2.z + xv.w * v2.w;
        qs = xv.x * w1.x + xv.y * w1.y + xv.z * w1.z + xv.w * w1.w;
        qd = xv.x * w2.x + xv.y * w2.y + xv.z * w2.z + xv.w * w2.w;
        ushort4 o;
        o.x = f2bf(xv.x); o.y = f2bf(xv.y); o.z = f2bf(xv.z); o.w = f2bf(xv.w);
        *(ushort4*)(xb + (size_t)n * FDIM + lane * 4) = o;
    }
    ps = wave_sum_bcast(ps);
    pd = wave_sum_bcast(pd);
    qs = wave_sum_bcast(qs);
    qd = wave_sum_bcast(qd);
    if (lane == 0) {
        float4 r = make_float4(ps, pd, qs, qd);
        *(float4*)(scal + (size_t)n * 4) = r;
    }
}

__global__ __launch_bounds__(256) void k_cvt(const float* __restrict__ src,
                                             unsigned short* __restrict__ dst, int n4) {
    int i = blockIdx.x * 256 + threadIdx.x;
    if (i >= n4) return;
    float4 v = *(const float4*)(src + (size_t)i * 4);
    ushort4 o;
    o.x = f2bf(v.x); o.y = f2bf(v.y); o.z = f2bf(v.z); o.w = f2bf(v.w);
    *(ushort4*)(dst + (size_t)i * 4) = o;
}

__global__ __launch_bounds__(256) void k_hist(const int* __restrict__ edge,
                                              const int* __restrict__ edgenh,
                                              int* __restrict__ counts) {
    int g = blockIdx.x * 256 + threadIdx.x;
    if (g >= EN) return;
    int s = (g < E1N) ? edge[g] : edgenh[g - E1N];
    atomicAdd(counts + s, 1);
}

__global__ __launch_bounds__(256) void k_scan1(const int* __restrict__ counts,
                                               int* __restrict__ incl,
                                               int* __restrict__ bsums) {
    __shared__ int tmp[256];
    int g = blockIdx.x * 256 + threadIdx.x;
    int v = (g < NN) ? counts[g] : 0;
    tmp[threadIdx.x] = v;
    __syncthreads();
    for (int off = 1; off < 256; off <<= 1) {
        int t = (threadIdx.x >= off) ? tmp[threadIdx.x - off] : 0;
        __syncthreads();
        tmp[threadIdx.x] += t;
        __syncthreads();
    }
    if (g < NN) incl[g] = tmp[threadIdx.x];
    if (threadIdx.x == 255) bsums[blockIdx.x] = tmp[255];
}

__global__ __launch_bounds__(256) void k_scan2(int* __restrict__ bsums, int nb) {
    __shared__ int tmp[256];
    int v = (threadIdx.x < nb) ? bsums[threadIdx.x] : 0;
    tmp[threadIdx.x] = v;
    __syncthreads();
    for (int off = 1; off < 256; off <<= 1) {
        int t = (threadIdx.x >= off) ? tmp[threadIdx.x - off] : 0;
        __syncthreads();
        tmp[threadIdx.x] += t;
        __syncthreads();
    }
    if (threadIdx.x < nb) bsums[threadIdx.x] = tmp[threadIdx.x] - v;  // exclusive
}

// incl -> exclusive offsets; also copy into fill (running cursor for scatter)
__global__ __launch_bounds__(256) void k_scan3(const int* __restrict__ counts,
                                               int* __restrict__ incl,
                                               const int* __restrict__ bsums,
                                               int* __restrict__ fill) {
    int g = blockIdx.x * 256 + threadIdx.x;
    if (g >= NN) return;
    int v = incl[g] - counts[g] + bsums[blockIdx.x];
    incl[g] = v;
    fill[g] = v;
}

// scatter (e, dst) pairs grouped by src
__global__ __launch_bounds__(256) void k_scatter(const int* __restrict__ edge,
                                                 const int* __restrict__ edgenh,
                                                 int* __restrict__ fill,
                                                 int2* __restrict__ sorted2) {
    int g = blockIdx.x * 256 + threadIdx.x;
    if (g >= EN) return;
    int s, d;
    if (g < E1N) { s = edge[g]; d = edge[E1N + g]; }
    else { s = edgenh[g - E1N]; d = edgenh[E2N + (g - E1N)]; }
    int pos = atomicAdd(fill + s, 1);
    sorted2[pos] = make_int2(g, d);
}

// Fused per-node pass, latency-optimized:
//  - whole edge list + scal gathers loaded LANE-PARALLEL up front (chunks of 64);
//    per-iteration record access is a 1-cycle readlane (no dependent load chain)
//  - 4-slot modulo-scheduled row pipeline: 3-4 rows (~4KB) in flight per wave
#define ISSUE(EV, XU, IDX) do {                                                   \
    int _e = __builtin_amdgcn_readlane(recx, (IDX));                              \
    int _d = __builtin_amdgcn_readlane(recy, (IDX));                              \
    const float* _er = (_e < E1N) ? ee + (size_t)_e * FDIM                        \
                                  : eenh + (size_t)(_e - E1N) * FDIM;             \
    if (lane < 50) {                                                              \
        EV = *(const float4*)(_er + lane * 4);                                    \
        XU = *(const ushort4*)(xb + (size_t)_d * FDIM + lane * 4);                \
    }                                                                             \
} while (0)

#define CONSUME(EV, XU, IDX) do {                                                 \
    float _pe = EV.x * v3.x + EV.y * v3.y + EV.z * v3.z + EV.w * v3.w;            \
    float _qe = EV.x * w3.x + EV.y * w3.y + EV.z * w3.z + EV.w * w3.w;            \
    _pe = wave_sum_bcast(_pe);                                                    \
    _qe = wave_sum_bcast(_qe);                                                    \
    float _sdy = readlane_f(sdy, (IDX));                                          \
    float _sdw = readlane_f(sdw, (IDX));                                          \
    float _z1 = scx + _sdy + _pe;                                                 \
    float _z2 = scz + _sdw + _qe + mb;                                            \
    float _l = _z1 > 0.f ? _z1 : 0.2f * _z1;                                      \
    float _e2 = __expf(2.f * _z2);                                                \
    float _t = 1.f - 2.f * __builtin_amdgcn_rcpf(_e2 + 1.f);                      \
    float _w = __expf(_l * _t * (-1.f / (float)EN));                              \
    _w = ((IDX) < m) ? _w : 0.f;                                                  \
    rs += _w;                                                                     \
    float _x0 = bf2f(XU.x), _x1 = bf2f(XU.y), _x2 = bf2f(XU.z), _x3 = bf2f(XU.w); \
    accx0 += _w * _x0; accx1 += _w * _x1; accx2 += _w * _x2; accx3 += _w * _x3;   \
    acce0 += _w * EV.x; acce1 += _w * EV.y; acce2 += _w * EV.z; acce3 += _w * EV.w; \
} while (0)

__global__ __launch_bounds__(256) void k_csr(const int2* __restrict__ sorted2,
                                             const int* __restrict__ offs,
                                             const int* __restrict__ counts,
                                             const float* __restrict__ ee,
                                             const float* __restrict__ eenh,
                                             const unsigned short* __restrict__ xb,
                                             const float* __restrict__ vall,
                                             const float* __restrict__ wall,
                                             const float* __restrict__ scal,
                                             const float* __restrict__ mlpb,
                                             float* __restrict__ rowsum,
                                             unsigned short* __restrict__ Tsb) {
    int tid = threadIdx.x, lane = tid & 63;
    int n = blockIdx.x * 4 + (tid >> 6);
    float4 v3 = make_float4(0, 0, 0, 0), w3 = v3;
    if (lane < 50) {
        v3 = *(const float4*)(vall + 400 + lane * 4);
        w3 = *(const float4*)(wall + 400 + lane * 4);
    }
    float scx = scal[(size_t)n * 4 + 0];
    float scz = scal[(size_t)n * 4 + 2];
    float mb = mlpb[0];
    int beg = offs[n], cnt = counts[n];
    float accx0 = 0, accx1 = 0, accx2 = 0, accx3 = 0;
    float acce0 = 0, acce1 = 0, acce2 = 0, acce3 = 0;
    float rs = 0.f;

    for (int c0 = 0; c0 < cnt; c0 += 64) {
        int m = cnt - c0; if (m > 64) m = 64;
        // lane-parallel edge-record + scal gather for this chunk
        int recx = 0, recy = 0;
        float sdy = 0.f, sdw = 0.f;
        if (lane < m) {
            int2 rr = sorted2[beg + c0 + lane];
            recx = rr.x; recy = rr.y;
            sdy = scal[(size_t)rr.y * 4 + 1];
            sdw = scal[(size_t)rr.y * 4 + 3];
        }
        int m4 = (m + 3) & ~3;   // padded; CONSUME masks wgt for IDX >= m
        float4 ev0 = make_float4(0,0,0,0), ev1 = ev0, ev2 = ev0, ev3 = ev0;
        ushort4 xu0 = {0,0,0,0}, xu1 = xu0, xu2 = xu0, xu3 = xu0;
        // prologue: fill 4 slots (m4 >= 4 whenever m >= 1)
        ISSUE(ev0, xu0, 0);
        ISSUE(ev1, xu1, 1);
        ISSUE(ev2, xu2, 2);
        ISSUE(ev3, xu3, 3);
        for (int i = 0; i < m4; i += 4) {
            CONSUME(ev0, xu0, i + 0); if (i + 4 < m4) ISSUE(ev0, xu0, i + 4);
            CONSUME(ev1, xu1, i + 1); if (i + 5 < m4) ISSUE(ev1, xu1, i + 5);
            CONSUME(ev2, xu2, i + 2); if (i + 6 < m4) ISSUE(ev2, xu2, i + 6);
            CONSUME(ev3, xu3, i + 3); if (i + 7 < m4) ISSUE(ev3, xu3, i + 7);
        }
    }

    if (lane == 0) rowsum[n] = rs;
    float inv = (cnt > 0) ? __builtin_amdgcn_rcpf(rs) : 0.f;
    if (lane < 50) {
        ushort4 o1, o2;
        o1.x = f2bf(accx0 * inv); o1.y = f2bf(accx1 * inv);
        o1.z = f2bf(accx2 * inv); o1.w = f2bf(accx3 * inv);
        o2.x = f2bf(acce0 * inv); o2.y = f2bf(acce1 * inv);
        o2.z = f2bf(acce2 * inv); o2.w = f2bf(acce3 * inv);
        *(ushort4*)(Tsb + (size_t)n * 400 + lane * 4) = o1;
        *(ushort4*)(Tsb + (size_t)n * 400 + 200 + lane * 4) = o2;
    }
}

// single fused GEMM: out = elu([x | T/rs] @ A^T), rowsum==0 -> 0
// K padded to 640: [0,200) from xb, [224,624) from Tsb, rest zero. B from ab (stride 600).
// XCD-chunked block swizzle: grid 3128 = 8*391.
__global__ __launch_bounds__(256) void k_gemm_fused(const unsigned short* __restrict__ xb,
                                                    const unsigned short* __restrict__ tsb,
                                                    const unsigned short* __restrict__ ab,
                                                    const float* __restrict__ rowsum,
                                                    float* __restrict__ out) {
    __shared__ unsigned short Al[64][40];
    __shared__ unsigned short Bl[64][40];
    int tid = threadIdx.x, w = tid >> 6, lane = tid & 63;
    int h = blockIdx.y * 4 + blockIdx.x;          // linear hw id, x fastest
    int g = (h & 7) * 391 + (h >> 3);             // bijective: 3128 = 8*391
    int by = g >> 2, bx = g & 3;
    f32x4 acc[4] = {};
    int r = tid >> 2, c = tid & 3;
    int arow = by * 64 + r;
    int brow = bx * 64 + r;
    bool inA = arow < NN;
    bool inB = brow < 200;
    const unsigned short* aPx = xb + (size_t)arow * 200;
    const unsigned short* aPt = tsb + (size_t)arow * 400;
    const unsigned short* bP = ab + (size_t)brow * 600;
    for (int k0 = 0; k0 < 640; k0 += 32) {
        int gk = k0 + c * 8;
        uint4 av = make_uint4(0, 0, 0, 0), bv = av;
        if (gk < 200) {
            if (inA) av = *(const uint4*)(aPx + gk);
            if (inB) bv = *(const uint4*)(bP + gk);
        } else if (gk >= 224 && gk < 624) {
            if (inA) av = *(const uint4*)(aPt + (gk - 224));
            if (inB) bv = *(const uint4*)(bP + gk - 24);  // a col 200 + (gk-224)
        }
        *(uint4*)&Al[r][c * 8] = av;
        *(uint4*)&Bl[r][c * 8] = bv;
        __syncthreads();
        short8 af = *(short8*)&Al[w * 16 + (lane & 15)][(lane >> 4) * 8];
        #pragma unroll
        for (int ct = 0; ct < 4; ++ct) {
            short8 bf = *(short8*)&Bl[ct * 16 + (lane & 15)][(lane >> 4) * 8];
            acc[ct] = __builtin_amdgcn_mfma_f32_16x16x32_bf16(af, bf, acc[ct], 0, 0, 0);
        }
        __syncthreads();
    }
    #pragma unroll
    for (int ct = 0; ct < 4; ++ct) {
        #pragma unroll
        for (int rr = 0; rr < 4; ++rr) {
            int grow = by * 64 + w * 16 + (lane >> 4) * 4 + rr;
            int gcol = bx * 64 + ct * 16 + (lane & 15);
            if (grow < NN && gcol < 200) {
                float rsv = rowsum[grow];
                float hh = acc[ct][rr];
                float o = (rsv == 0.f) ? 0.f : (hh > 0.f ? hh : expm1f(hh));
                out[(size_t)grow * 200 + gcol] = o;
            }
        }
    }
}

extern "C" void kernel_launch(void* const* d_in, const int* in_sizes, int n_in,
                              void* d_out, int out_size, void* d_ws, size_t ws_size,
                              hipStream_t stream) {
    const float* x      = (const float*)d_in[0];
    const int*   edge   = (const int*)d_in[1];
    const float* ee     = (const float*)d_in[2];
    const int*   edgenh = (const int*)d_in[3];
    const float* eenh   = (const float*)d_in[4];
    const float* a      = (const float*)d_in[5];
    const float* a2     = (const float*)d_in[6];
    const float* mlpw   = (const float*)d_in[7];
    const float* mlpb   = (const float*)d_in[8];

    float* ws = (float*)d_ws;
    float* vall   = ws + VALL_OFF;
    float* wall   = ws + WALL_OFF;
    float* scal   = ws + SCAL_OFF;
    float* rowsum = ws + RS_OFF;
    int*   counts = (int*)(ws + CNT_OFF);
    int*   fill   = (int*)(ws + FILL_OFF);
    int*   incl   = (int*)(ws + INCL_OFF);
    int*   bsums  = (int*)(ws + BSUM_OFF);
    int2*  sorted2 = (int2*)(ws + SORT_OFF);
    unsigned short* xb  = (unsigned short*)(ws + XB_OFF);
    unsigned short* ab  = (unsigned short*)(ws + AB_OFF);
    unsigned short* tsb = (unsigned short*)(ws + TSB_OFF);

    hipMemsetAsync(counts, 0, (size_t)(2 * NN) * sizeof(int), stream);

    k_coeffs<<<3, 256, 0, stream>>>(a, a2, mlpw, vall, wall);
    k_node_scal<<<NN / 4, 256, 0, stream>>>(x, vall, wall, scal, xb);
    k_cvt<<<(200 * 600 / 4 + 255) / 256, 256, 0, stream>>>(a, ab, 200 * 600 / 4);

    k_hist<<<(EN + 255) / 256, 256, 0, stream>>>(edge, edgenh, counts);
    int nb = (NN + 255) / 256;
    k_scan1<<<nb, 256, 0, stream>>>(counts, incl, bsums);
    k_scan2<<<1, 256, 0, stream>>>(bsums, nb);
    k_scan3<<<nb, 256, 0, stream>>>(counts, incl, bsums, fill);
    k_scatter<<<(EN + 255) / 256, 256, 0, stream>>>(edge, edgenh, fill, sorted2);

    k_csr<<<NN / 4, 256, 0, stream>>>(sorted2, incl, counts, ee, eenh, xb,
                                      vall, wall, scal, mlpb, rowsum, tsb);

    dim3 gg(4, (NN + 63) / 64);
    k_gemm_fused<<<gg, 256, 0, stream>>>(xb, tsb, ab, rowsum, (float*)d_out);
}